// Round 4
// baseline (878.598 us; speedup 1.0000x reference)
//
#include <hip/hip_runtime.h>

#define N_NODES 100000
#define N_EDGES 1600000
#define HIDDEN  128
#define EMB_DIM 122       // HIDDEN - N_STRUCT
#define NSTRUCT 6
#define BN_EPS  1e-5f

// ---------------- degree count (dst side) ----------------
__global__ void k_count_deg(const int* __restrict__ dst, int* __restrict__ deg) {
    int i = blockIdx.x * blockDim.x + threadIdx.x;
    if (i < N_EDGES) atomicAdd(&deg[dst[i]], 1);
}

// ---------------- exclusive scan of deg -> ptr ----------------
#define SCAN_B 256
__global__ void k_scan1(const int* __restrict__ deg, int* __restrict__ bsum) {
    __shared__ int s[SCAN_B];
    int t = threadIdx.x;
    int i = blockIdx.x * SCAN_B + t;
    s[t] = (i < N_NODES) ? deg[i] : 0;
    __syncthreads();
    for (int off = SCAN_B / 2; off > 0; off >>= 1) {
        if (t < off) s[t] += s[t + off];
        __syncthreads();
    }
    if (t == 0) bsum[blockIdx.x] = s[0];
}

// parallel single-block scan over the (<=512) block sums
__global__ void k_scan2(int* __restrict__ bsum, int nb, int* __restrict__ ptrN) {
    __shared__ int s[512];
    int t = threadIdx.x;
    int v = (t < nb) ? bsum[t] : 0;
    s[t] = v;
    __syncthreads();
    for (int off = 1; off < 512; off <<= 1) {
        int u = (t >= off) ? s[t - off] : 0;
        __syncthreads();
        s[t] += u;
        __syncthreads();
    }
    if (t < nb) bsum[t] = s[t] - v;          // exclusive block offset
    if (t == nb - 1) *ptrN = s[t];           // total = ptr[N_NODES]
}

__global__ void k_scan3(const int* __restrict__ deg, const int* __restrict__ bsum,
                        int* __restrict__ ptr) {
    __shared__ int s[SCAN_B];
    int t = threadIdx.x;
    int i = blockIdx.x * SCAN_B + t;
    int v = (i < N_NODES) ? deg[i] : 0;
    s[t] = v;
    __syncthreads();
    for (int off = 1; off < SCAN_B; off <<= 1) {
        int u = (t >= off) ? s[t - off] : 0;
        __syncthreads();
        s[t] += u;
        __syncthreads();
    }
    if (i < N_NODES) ptr[i] = bsum[blockIdx.x] + s[t] - v;  // exclusive
}

// ---------------- CSR bucket fill: srcs + norm (dinv folded in) ----------------
__global__ void k_fill(const int* __restrict__ src, const int* __restrict__ dst,
                       const int* __restrict__ deg, const int* __restrict__ ptr,
                       int* __restrict__ fill, int* __restrict__ srcs,
                       float* __restrict__ norms) {
    int i = blockIdx.x * blockDim.x + threadIdx.x;
    if (i < N_EDGES) {
        int s = src[i], d = dst[i];
        int ds = deg[s], dd = deg[d];
        float ns = (ds > 0) ? rsqrtf((float)ds) : 0.0f;
        float nd = (dd > 0) ? rsqrtf((float)dd) : 0.0f;
        int pos = ptr[d] + atomicAdd(&fill[d], 1);
        srcs[pos]  = s;
        norms[pos] = ns * nd;
    }
}

// ---------------- node feature init: x = [emb || relu(sf @ pw + pb)] ----------------
__global__ void k_node_init(const float* __restrict__ emb, const float* __restrict__ sfeat,
                            const float* __restrict__ pw, const float* __restrict__ pb,
                            float* __restrict__ x) {
    int idx = blockIdx.x * blockDim.x + threadIdx.x;
    if (idx >= N_NODES * HIDDEN) return;
    int n = idx >> 7, c = idx & 127;
    float v;
    if (c < EMB_DIM) {
        v = emb[n * EMB_DIM + c];
    } else {
        int j = c - EMB_DIM;
        float a = pb[j];
        #pragma unroll
        for (int k = 0; k < NSTRUCT; ++k) a += sfeat[n * NSTRUCT + k] * pw[k * NSTRUCT + j];
        v = fmaxf(a, 0.0f);
    }
    x[idx] = v;
}

// ---------------- GEMM: h = x @ W  (fp32 vector, LDS-tiled) ----------------
__global__ __launch_bounds__(256, 3)
void k_gemm(const float* __restrict__ x, const float* __restrict__ W,
            float* __restrict__ h) {
    __shared__ float Ws[64 * HIDDEN];   // 32 KB
    __shared__ float xs[64][65];        // 16.6 KB padded

    const int tid = threadIdx.x;
    const int n0  = blockIdx.x * 64;
    const int cg  = tid & 15;
    const int rg  = tid >> 4;
    const int c0  = cg * 4;
    const int r0  = rg * 4;

    float acc[4][8];
    #pragma unroll
    for (int i = 0; i < 4; ++i)
        #pragma unroll
        for (int j = 0; j < 8; ++j) acc[i][j] = 0.0f;

    for (int kk = 0; kk < HIDDEN; kk += 64) {
        for (int i = tid; i < 64 * HIDDEN; i += 256) Ws[i] = W[kk * HIDDEN + i];
        for (int i = tid; i < 64 * 64; i += 256) {
            int r = i >> 6, k = i & 63;
            int gn = n0 + r;
            xs[r][k] = (gn < N_NODES) ? x[(size_t)gn * HIDDEN + kk + k] : 0.0f;
        }
        __syncthreads();

        #pragma unroll 4
        for (int k = 0; k < 64; ++k) {
            float4 wa = *reinterpret_cast<const float4*>(&Ws[k * HIDDEN + c0]);
            float4 wb = *reinterpret_cast<const float4*>(&Ws[k * HIDDEN + c0 + 64]);
            #pragma unroll
            for (int i = 0; i < 4; ++i) {
                float xv = xs[r0 + i][k];
                acc[i][0] = fmaf(xv, wa.x, acc[i][0]);
                acc[i][1] = fmaf(xv, wa.y, acc[i][1]);
                acc[i][2] = fmaf(xv, wa.z, acc[i][2]);
                acc[i][3] = fmaf(xv, wa.w, acc[i][3]);
                acc[i][4] = fmaf(xv, wb.x, acc[i][4]);
                acc[i][5] = fmaf(xv, wb.y, acc[i][5]);
                acc[i][6] = fmaf(xv, wb.z, acc[i][6]);
                acc[i][7] = fmaf(xv, wb.w, acc[i][7]);
            }
        }
        __syncthreads();
    }

    #pragma unroll
    for (int i = 0; i < 4; ++i) {
        int gn = n0 + r0 + i;
        if (gn < N_NODES) {
            float4 o0 = make_float4(acc[i][0], acc[i][1], acc[i][2], acc[i][3]);
            float4 o1 = make_float4(acc[i][4], acc[i][5], acc[i][6], acc[i][7]);
            *reinterpret_cast<float4*>(&h[(size_t)gn * HIDDEN + c0])      = o0;
            *reinterpret_cast<float4*>(&h[(size_t)gn * HIDDEN + c0 + 64]) = o1;
        }
    }
}

// ---------------- aggregation + fused bias/BN/ReLU/residual ----------------
// One wave per node; lane owns cols {2*lane, 2*lane+1} -> wave gather of one
// h row = one contiguous 512B read. Two accumulator pairs break the FMA chain.
__global__ __launch_bounds__(256)
void k_agg(const float* __restrict__ h, const int* __restrict__ ptr,
           const int* __restrict__ srcs, const float* __restrict__ norms,
           const float* __restrict__ bias, const float* __restrict__ mean,
           const float* __restrict__ var, const float* __restrict__ gamma,
           const float* __restrict__ beta,
           const float* __restrict__ xprev, int has_resid,
           float* __restrict__ out) {
    int node = blockIdx.x * 4 + (threadIdx.x >> 6);
    if (node >= N_NODES) return;
    int lane = threadIdx.x & 63;
    int s = ptr[node], e = ptr[node + 1];
    const int c0 = lane * 2;

    // issue epilogue param loads early (overlap with gather loop)
    float2 bi = *reinterpret_cast<const float2*>(bias  + c0);
    float2 mu = *reinterpret_cast<const float2*>(mean  + c0);
    float2 va = *reinterpret_cast<const float2*>(var   + c0);
    float2 ga = *reinterpret_cast<const float2*>(gamma + c0);
    float2 be = *reinterpret_cast<const float2*>(beta  + c0);

    float a0 = 0.0f, a1 = 0.0f, b0 = 0.0f, b1 = 0.0f;

    for (int j0 = s; j0 < e; j0 += 64) {
        int nb  = min(64, e - j0);
        int idx = j0 + lane;
        int   mys = (idx < e) ? srcs[idx]  : 0;
        float myn = (idx < e) ? norms[idx] : 0.0f;
        int j = 0;
        #pragma unroll 2
        for (; j + 1 < nb; j += 2) {
            int   sv0 = __builtin_amdgcn_readlane(mys, j);
            float nv0 = __int_as_float(__builtin_amdgcn_readlane(__float_as_int(myn), j));
            int   sv1 = __builtin_amdgcn_readlane(mys, j + 1);
            float nv1 = __int_as_float(__builtin_amdgcn_readlane(__float_as_int(myn), j + 1));
            float2 h0 = *reinterpret_cast<const float2*>(h + ((size_t)sv0 << 7) + c0);
            float2 h1 = *reinterpret_cast<const float2*>(h + ((size_t)sv1 << 7) + c0);
            a0 = fmaf(nv0, h0.x, a0);
            a1 = fmaf(nv0, h0.y, a1);
            b0 = fmaf(nv1, h1.x, b0);
            b1 = fmaf(nv1, h1.y, b1);
        }
        if (j < nb) {
            int   sv = __builtin_amdgcn_readlane(mys, j);
            float nv = __int_as_float(__builtin_amdgcn_readlane(__float_as_int(myn), j));
            float2 hv = *reinterpret_cast<const float2*>(h + ((size_t)sv << 7) + c0);
            a0 = fmaf(nv, hv.x, a0);
            a1 = fmaf(nv, hv.y, a1);
        }
    }
    float acc0 = a0 + b0, acc1 = a1 + b1;

    float s0 = ga.x * rsqrtf(va.x + BN_EPS);
    float s1 = ga.y * rsqrtf(va.y + BN_EPS);
    float y0 = (acc0 + bi.x - mu.x) * s0 + be.x;
    float y1 = (acc1 + bi.y - mu.y) * s1 + be.y;
    y0 = fmaxf(y0, 0.0f);
    y1 = fmaxf(y1, 0.0f);
    size_t o = ((size_t)node << 7) + c0;
    if (has_resid) {
        y0 += 0.5f * xprev[o];
        y1 += 0.5f * xprev[o + 1];
    }
    out[o]     = y0;
    out[o + 1] = y1;
}

// ---------------- launch ----------------
extern "C" void kernel_launch(void* const* d_in, const int* in_sizes, int n_in,
                              void* d_out, int out_size, void* d_ws, size_t ws_size,
                              hipStream_t stream) {
    const int*   ei    = (const int*)d_in[0];
    const int*   src   = ei;
    const int*   dst   = ei + N_EDGES;
    const float* sfeat = (const float*)d_in[1];
    const float* emb   = (const float*)d_in[2];
    const float* pw    = (const float*)d_in[3];
    const float* pb    = (const float*)d_in[4];
    const float* convw = (const float*)d_in[5];
    const float* convb = (const float*)d_in[6];
    const float* gamma = (const float*)d_in[7];
    const float* beta  = (const float*)d_in[8];
    const float* mean  = (const float*)d_in[9];
    const float* var   = (const float*)d_in[10];
    float* out = (float*)d_out;

    char* wsc = (char*)d_ws;
    auto alloc = [&](size_t bytes) -> void* {
        void* p = (void*)wsc;
        wsc += (bytes + 255) & ~(size_t)255;
        return p;
    };
    int*   deg   = (int*)  alloc(N_NODES * sizeof(int));
    int*   fill  = (int*)  alloc(N_NODES * sizeof(int));
    int*   ptr   = (int*)  alloc((N_NODES + 1) * sizeof(int));
    int*   bsum  = (int*)  alloc(512 * sizeof(int));
    int*   srcs  = (int*)  alloc(N_EDGES * sizeof(int));
    float* norms = (float*)alloc(N_EDGES * sizeof(float));
    float* bufA  = (float*)alloc((size_t)N_NODES * HIDDEN * sizeof(float));
    float* bufB  = (float*)alloc((size_t)N_NODES * HIDDEN * sizeof(float));

    const int nb = (N_NODES + SCAN_B - 1) / SCAN_B;   // 391

    hipMemsetAsync(deg,  0, N_NODES * sizeof(int), stream);
    hipMemsetAsync(fill, 0, N_NODES * sizeof(int), stream);

    k_count_deg<<<N_EDGES / 256, 256, 0, stream>>>(dst, deg);
    k_scan1<<<nb, SCAN_B, 0, stream>>>(deg, bsum);
    k_scan2<<<1, 512, 0, stream>>>(bsum, nb, &ptr[N_NODES]);
    k_scan3<<<nb, SCAN_B, 0, stream>>>(deg, bsum, ptr);
    k_fill<<<N_EDGES / 256, 256, 0, stream>>>(src, dst, deg, ptr, fill, srcs, norms);
    k_node_init<<<(N_NODES * HIDDEN) / 256, 256, 0, stream>>>(emb, sfeat, pw, pb, bufA);

    const int ggrid = (N_NODES + 63) / 64;     // 1563
    const int agrid = (N_NODES + 3) / 4;       // 25000

    k_gemm<<<ggrid, 256, 0, stream>>>(bufA, convw + 0 * HIDDEN * HIDDEN, bufB);
    k_agg<<<agrid, 256, 0, stream>>>(bufB, ptr, srcs, norms,
                                     convb + 0 * HIDDEN, mean + 0 * HIDDEN, var + 0 * HIDDEN,
                                     gamma + 0 * HIDDEN, beta + 0 * HIDDEN,
                                     nullptr, 0, bufA);
    k_gemm<<<ggrid, 256, 0, stream>>>(bufA, convw + 1 * HIDDEN * HIDDEN, bufB);
    k_agg<<<agrid, 256, 0, stream>>>(bufB, ptr, srcs, norms,
                                     convb + 1 * HIDDEN, mean + 1 * HIDDEN, var + 1 * HIDDEN,
                                     gamma + 1 * HIDDEN, beta + 1 * HIDDEN,
                                     bufA, 1, out);
    k_gemm<<<ggrid, 256, 0, stream>>>(out, convw + 2 * HIDDEN * HIDDEN, bufB);
    k_agg<<<agrid, 256, 0, stream>>>(bufB, ptr, srcs, norms,
                                     convb + 2 * HIDDEN, mean + 2 * HIDDEN, var + 2 * HIDDEN,
                                     gamma + 2 * HIDDEN, beta + 2 * HIDDEN,
                                     out, 1, out);
    (void)in_sizes; (void)n_in; (void)out_size; (void)ws_size;
}

// Round 5
// 847.772 us; speedup vs baseline: 1.0364x; 1.0364x over previous
//
#include <hip/hip_runtime.h>

#define N_NODES 100000
#define N_EDGES 1600000
#define HIDDEN  128
#define EMB_DIM 122       // HIDDEN - N_STRUCT
#define NSTRUCT 6
#define BN_EPS  1e-5f

// ---------------- degree count (dst side) ----------------
__global__ void k_count_deg(const int* __restrict__ dst, int* __restrict__ deg) {
    int i = blockIdx.x * blockDim.x + threadIdx.x;
    if (i < N_EDGES) atomicAdd(&deg[dst[i]], 1);
}

// ---------------- exclusive scan of deg -> ptr ----------------
#define SCAN_B 256
__global__ void k_scan1(const int* __restrict__ deg, int* __restrict__ bsum) {
    __shared__ int s[SCAN_B];
    int t = threadIdx.x;
    int i = blockIdx.x * SCAN_B + t;
    s[t] = (i < N_NODES) ? deg[i] : 0;
    __syncthreads();
    for (int off = SCAN_B / 2; off > 0; off >>= 1) {
        if (t < off) s[t] += s[t + off];
        __syncthreads();
    }
    if (t == 0) bsum[blockIdx.x] = s[0];
}

// parallel single-block scan over the (<=512) block sums
__global__ void k_scan2(int* __restrict__ bsum, int nb, int* __restrict__ ptrN) {
    __shared__ int s[512];
    int t = threadIdx.x;
    int v = (t < nb) ? bsum[t] : 0;
    s[t] = v;
    __syncthreads();
    for (int off = 1; off < 512; off <<= 1) {
        int u = (t >= off) ? s[t - off] : 0;
        __syncthreads();
        s[t] += u;
        __syncthreads();
    }
    if (t < nb) bsum[t] = s[t] - v;          // exclusive block offset
    if (t == nb - 1) *ptrN = s[t];           // total = ptr[N_NODES]
}

__global__ void k_scan3(const int* __restrict__ deg, const int* __restrict__ bsum,
                        int* __restrict__ ptr) {
    __shared__ int s[SCAN_B];
    int t = threadIdx.x;
    int i = blockIdx.x * SCAN_B + t;
    int v = (i < N_NODES) ? deg[i] : 0;
    s[t] = v;
    __syncthreads();
    for (int off = 1; off < SCAN_B; off <<= 1) {
        int u = (t >= off) ? s[t - off] : 0;
        __syncthreads();
        s[t] += u;
        __syncthreads();
    }
    if (i < N_NODES) ptr[i] = bsum[blockIdx.x] + s[t] - v;  // exclusive
}

// ---------------- CSR bucket fill: fused 8B edge record {src, norm} ----------------
// One int2 store per edge -> one dirty cacheline instead of two (write-allocate
// traffic was 155MB measured with separate srcs/norms arrays).
__global__ void k_fill(const int* __restrict__ src, const int* __restrict__ dst,
                       const int* __restrict__ deg, const int* __restrict__ ptr,
                       int* __restrict__ fill, int2* __restrict__ edges) {
    int i = blockIdx.x * blockDim.x + threadIdx.x;
    if (i < N_EDGES) {
        int s = src[i], d = dst[i];
        int ds = deg[s], dd = deg[d];
        float ns = (ds > 0) ? rsqrtf((float)ds) : 0.0f;
        float nd = (dd > 0) ? rsqrtf((float)dd) : 0.0f;
        int pos = ptr[d] + atomicAdd(&fill[d], 1);
        edges[pos] = make_int2(s, __float_as_int(ns * nd));
    }
}

// ---------------- node feature init: x = [emb || relu(sf @ pw + pb)] ----------------
__global__ void k_node_init(const float* __restrict__ emb, const float* __restrict__ sfeat,
                            const float* __restrict__ pw, const float* __restrict__ pb,
                            float* __restrict__ x) {
    int idx = blockIdx.x * blockDim.x + threadIdx.x;
    if (idx >= N_NODES * HIDDEN) return;
    int n = idx >> 7, c = idx & 127;
    float v;
    if (c < EMB_DIM) {
        v = emb[n * EMB_DIM + c];
    } else {
        int j = c - EMB_DIM;
        float a = pb[j];
        #pragma unroll
        for (int k = 0; k < NSTRUCT; ++k) a += sfeat[n * NSTRUCT + k] * pw[k * NSTRUCT + j];
        v = fmaxf(a, 0.0f);
    }
    x[idx] = v;
}

// ---------------- GEMM: h = x @ W  (fp32 vector, LDS-tiled) ----------------
__global__ __launch_bounds__(256, 3)
void k_gemm(const float* __restrict__ x, const float* __restrict__ W,
            float* __restrict__ h) {
    __shared__ float Ws[64 * HIDDEN];   // 32 KB
    __shared__ float xs[64][65];        // 16.6 KB padded

    const int tid = threadIdx.x;
    const int n0  = blockIdx.x * 64;
    const int cg  = tid & 15;
    const int rg  = tid >> 4;
    const int c0  = cg * 4;
    const int r0  = rg * 4;

    float acc[4][8];
    #pragma unroll
    for (int i = 0; i < 4; ++i)
        #pragma unroll
        for (int j = 0; j < 8; ++j) acc[i][j] = 0.0f;

    for (int kk = 0; kk < HIDDEN; kk += 64) {
        for (int i = tid; i < 64 * HIDDEN; i += 256) Ws[i] = W[kk * HIDDEN + i];
        for (int i = tid; i < 64 * 64; i += 256) {
            int r = i >> 6, k = i & 63;
            int gn = n0 + r;
            xs[r][k] = (gn < N_NODES) ? x[(size_t)gn * HIDDEN + kk + k] : 0.0f;
        }
        __syncthreads();

        #pragma unroll 4
        for (int k = 0; k < 64; ++k) {
            float4 wa = *reinterpret_cast<const float4*>(&Ws[k * HIDDEN + c0]);
            float4 wb = *reinterpret_cast<const float4*>(&Ws[k * HIDDEN + c0 + 64]);
            #pragma unroll
            for (int i = 0; i < 4; ++i) {
                float xv = xs[r0 + i][k];
                acc[i][0] = fmaf(xv, wa.x, acc[i][0]);
                acc[i][1] = fmaf(xv, wa.y, acc[i][1]);
                acc[i][2] = fmaf(xv, wa.z, acc[i][2]);
                acc[i][3] = fmaf(xv, wa.w, acc[i][3]);
                acc[i][4] = fmaf(xv, wb.x, acc[i][4]);
                acc[i][5] = fmaf(xv, wb.y, acc[i][5]);
                acc[i][6] = fmaf(xv, wb.z, acc[i][6]);
                acc[i][7] = fmaf(xv, wb.w, acc[i][7]);
            }
        }
        __syncthreads();
    }

    #pragma unroll
    for (int i = 0; i < 4; ++i) {
        int gn = n0 + r0 + i;
        if (gn < N_NODES) {
            float4 o0 = make_float4(acc[i][0], acc[i][1], acc[i][2], acc[i][3]);
            float4 o1 = make_float4(acc[i][4], acc[i][5], acc[i][6], acc[i][7]);
            *reinterpret_cast<float4*>(&h[(size_t)gn * HIDDEN + c0])      = o0;
            *reinterpret_cast<float4*>(&h[(size_t)gn * HIDDEN + c0 + 64]) = o1;
        }
    }
}

// ---------------- aggregation + fused bias/BN/ReLU/residual ----------------
// One wave per node. Lane layout: half = lane>>5, sl = lane&31; lane owns cols
// 4*sl..4*sl+3 (float4, 16B/lane). Lanes 0-31 process even edges, lanes 32-63
// odd edges -> each global_load_dwordx4 covers TWO h rows (1KB/wave-inst).
// Cross-half __shfl_xor(32) reduce at the end; lanes 0-31 write float4.
__global__ __launch_bounds__(256)
void k_agg(const float* __restrict__ h, const int* __restrict__ ptr,
           const int2* __restrict__ edges,
           const float* __restrict__ bias, const float* __restrict__ mean,
           const float* __restrict__ var, const float* __restrict__ gamma,
           const float* __restrict__ beta,
           const float* __restrict__ xprev, int has_resid,
           float* __restrict__ out) {
    int node = blockIdx.x * 4 + (threadIdx.x >> 6);
    if (node >= N_NODES) return;
    const int lane = threadIdx.x & 63;
    const int half = lane >> 5;          // 0: even edges, 1: odd edges
    const int sl   = lane & 31;
    const int c0   = sl * 4;
    int s = ptr[node], e = ptr[node + 1];

    float4 accA = make_float4(0.f, 0.f, 0.f, 0.f);
    float4 accB = make_float4(0.f, 0.f, 0.f, 0.f);

    for (int j0 = s; j0 < e; j0 += 64) {
        int nb  = min(64, e - j0);
        int idx = j0 + lane;
        int2 rec = (idx < e) ? edges[idx] : make_int2(0, 0);
        int jj = 0;
        // 4 edges per iteration, 2 independent 16B loads in flight
        for (; jj + 3 < nb; jj += 4) {
            int   s0 = __builtin_amdgcn_readlane(rec.x, jj);
            int   s1 = __builtin_amdgcn_readlane(rec.x, jj + 1);
            int   s2 = __builtin_amdgcn_readlane(rec.x, jj + 2);
            int   s3 = __builtin_amdgcn_readlane(rec.x, jj + 3);
            float n0 = __int_as_float(__builtin_amdgcn_readlane(rec.y, jj));
            float n1 = __int_as_float(__builtin_amdgcn_readlane(rec.y, jj + 1));
            float n2 = __int_as_float(__builtin_amdgcn_readlane(rec.y, jj + 2));
            float n3 = __int_as_float(__builtin_amdgcn_readlane(rec.y, jj + 3));
            int   svA = half ? s1 : s0;  float nvA = half ? n1 : n0;
            int   svB = half ? s3 : s2;  float nvB = half ? n3 : n2;
            float4 hA = *reinterpret_cast<const float4*>(h + ((size_t)svA << 7) + c0);
            float4 hB = *reinterpret_cast<const float4*>(h + ((size_t)svB << 7) + c0);
            accA.x = fmaf(nvA, hA.x, accA.x);
            accA.y = fmaf(nvA, hA.y, accA.y);
            accA.z = fmaf(nvA, hA.z, accA.z);
            accA.w = fmaf(nvA, hA.w, accA.w);
            accB.x = fmaf(nvB, hB.x, accB.x);
            accB.y = fmaf(nvB, hB.y, accB.y);
            accB.z = fmaf(nvB, hB.z, accB.z);
            accB.w = fmaf(nvB, hB.w, accB.w);
        }
        // tail: 2 edges (or 1) at a time
        for (; jj < nb; jj += 2) {
            int   s0 = __builtin_amdgcn_readlane(rec.x, jj);
            float n0 = __int_as_float(__builtin_amdgcn_readlane(rec.y, jj));
            int s1v = 0; float n1v = 0.0f;
            if (jj + 1 < nb) {
                s1v = __builtin_amdgcn_readlane(rec.x, jj + 1);
                n1v = __int_as_float(__builtin_amdgcn_readlane(rec.y, jj + 1));
            }
            int   sv = half ? s1v : s0;
            float nv = half ? n1v : n0;
            float4 hv = *reinterpret_cast<const float4*>(h + ((size_t)sv << 7) + c0);
            accA.x = fmaf(nv, hv.x, accA.x);
            accA.y = fmaf(nv, hv.y, accA.y);
            accA.z = fmaf(nv, hv.z, accA.z);
            accA.w = fmaf(nv, hv.w, accA.w);
        }
    }

    float4 acc;
    acc.x = accA.x + accB.x;
    acc.y = accA.y + accB.y;
    acc.z = accA.z + accB.z;
    acc.w = accA.w + accB.w;
    // combine the two edge-halves (cols are the same on lane and lane^32)
    acc.x += __shfl_xor(acc.x, 32);
    acc.y += __shfl_xor(acc.y, 32);
    acc.z += __shfl_xor(acc.z, 32);
    acc.w += __shfl_xor(acc.w, 32);

    if (half == 0) {
        float4 bi = *reinterpret_cast<const float4*>(bias  + c0);
        float4 mu = *reinterpret_cast<const float4*>(mean  + c0);
        float4 va = *reinterpret_cast<const float4*>(var   + c0);
        float4 ga = *reinterpret_cast<const float4*>(gamma + c0);
        float4 be = *reinterpret_cast<const float4*>(beta  + c0);
        float4 y;
        y.x = fmaxf((acc.x + bi.x - mu.x) * (ga.x * rsqrtf(va.x + BN_EPS)) + be.x, 0.0f);
        y.y = fmaxf((acc.y + bi.y - mu.y) * (ga.y * rsqrtf(va.y + BN_EPS)) + be.y, 0.0f);
        y.z = fmaxf((acc.z + bi.z - mu.z) * (ga.z * rsqrtf(va.z + BN_EPS)) + be.z, 0.0f);
        y.w = fmaxf((acc.w + bi.w - mu.w) * (ga.w * rsqrtf(va.w + BN_EPS)) + be.w, 0.0f);
        size_t o = ((size_t)node << 7) + c0;
        if (has_resid) {
            float4 xp = *reinterpret_cast<const float4*>(xprev + o);
            y.x += 0.5f * xp.x;
            y.y += 0.5f * xp.y;
            y.z += 0.5f * xp.z;
            y.w += 0.5f * xp.w;
        }
        *reinterpret_cast<float4*>(out + o) = y;
    }
}

// ---------------- launch ----------------
extern "C" void kernel_launch(void* const* d_in, const int* in_sizes, int n_in,
                              void* d_out, int out_size, void* d_ws, size_t ws_size,
                              hipStream_t stream) {
    const int*   ei    = (const int*)d_in[0];
    const int*   src   = ei;
    const int*   dst   = ei + N_EDGES;
    const float* sfeat = (const float*)d_in[1];
    const float* emb   = (const float*)d_in[2];
    const float* pw    = (const float*)d_in[3];
    const float* pb    = (const float*)d_in[4];
    const float* convw = (const float*)d_in[5];
    const float* convb = (const float*)d_in[6];
    const float* gamma = (const float*)d_in[7];
    const float* beta  = (const float*)d_in[8];
    const float* mean  = (const float*)d_in[9];
    const float* var   = (const float*)d_in[10];
    float* out = (float*)d_out;

    char* wsc = (char*)d_ws;
    auto alloc = [&](size_t bytes) -> void* {
        void* p = (void*)wsc;
        wsc += (bytes + 255) & ~(size_t)255;
        return p;
    };
    int*   deg   = (int*)  alloc(N_NODES * sizeof(int));
    int*   fill  = (int*)  alloc(N_NODES * sizeof(int));
    int*   ptr   = (int*)  alloc((N_NODES + 1) * sizeof(int));
    int*   bsum  = (int*)  alloc(512 * sizeof(int));
    int2*  edges = (int2*) alloc((size_t)N_EDGES * sizeof(int2));
    float* bufA  = (float*)alloc((size_t)N_NODES * HIDDEN * sizeof(float));
    float* bufB  = (float*)alloc((size_t)N_NODES * HIDDEN * sizeof(float));

    const int nb = (N_NODES + SCAN_B - 1) / SCAN_B;   // 391

    hipMemsetAsync(deg,  0, N_NODES * sizeof(int), stream);
    hipMemsetAsync(fill, 0, N_NODES * sizeof(int), stream);

    k_count_deg<<<N_EDGES / 256, 256, 0, stream>>>(dst, deg);
    k_scan1<<<nb, SCAN_B, 0, stream>>>(deg, bsum);
    k_scan2<<<1, 512, 0, stream>>>(bsum, nb, &ptr[N_NODES]);
    k_scan3<<<nb, SCAN_B, 0, stream>>>(deg, bsum, ptr);
    k_fill<<<N_EDGES / 256, 256, 0, stream>>>(src, dst, deg, ptr, fill, edges);
    k_node_init<<<(N_NODES * HIDDEN) / 256, 256, 0, stream>>>(emb, sfeat, pw, pb, bufA);

    const int ggrid = (N_NODES + 63) / 64;     // 1563
    const int agrid = (N_NODES + 3) / 4;       // 25000

    k_gemm<<<ggrid, 256, 0, stream>>>(bufA, convw + 0 * HIDDEN * HIDDEN, bufB);
    k_agg<<<agrid, 256, 0, stream>>>(bufB, ptr, edges,
                                     convb + 0 * HIDDEN, mean + 0 * HIDDEN, var + 0 * HIDDEN,
                                     gamma + 0 * HIDDEN, beta + 0 * HIDDEN,
                                     nullptr, 0, bufA);
    k_gemm<<<ggrid, 256, 0, stream>>>(bufA, convw + 1 * HIDDEN * HIDDEN, bufB);
    k_agg<<<agrid, 256, 0, stream>>>(bufB, ptr, edges,
                                     convb + 1 * HIDDEN, mean + 1 * HIDDEN, var + 1 * HIDDEN,
                                     gamma + 1 * HIDDEN, beta + 1 * HIDDEN,
                                     bufA, 1, out);
    k_gemm<<<ggrid, 256, 0, stream>>>(out, convw + 2 * HIDDEN * HIDDEN, bufB);
    k_agg<<<agrid, 256, 0, stream>>>(bufB, ptr, edges,
                                     convb + 2 * HIDDEN, mean + 2 * HIDDEN, var + 2 * HIDDEN,
                                     gamma + 2 * HIDDEN, beta + 2 * HIDDEN,
                                     out, 1, out);
    (void)in_sizes; (void)n_in; (void)out_size; (void)ws_size;
}

// Round 6
// 712.084 us; speedup vs baseline: 1.2338x; 1.1906x over previous
//
#include <hip/hip_runtime.h>
#include <hip/hip_fp16.h>

#define N_NODES 100000
#define N_EDGES 1600000
#define HIDDEN  128
#define EMB_DIM 122       // HIDDEN - N_STRUCT
#define NSTRUCT 6
#define BN_EPS  1e-5f

// ---------------- degree count (dst side) ----------------
__global__ void k_count_deg(const int* __restrict__ dst, int* __restrict__ deg) {
    int i = blockIdx.x * blockDim.x + threadIdx.x;
    if (i < N_EDGES) atomicAdd(&deg[dst[i]], 1);
}

// ---------------- exclusive scan of deg -> ptr ----------------
#define SCAN_B 256
__global__ void k_scan1(const int* __restrict__ deg, int* __restrict__ bsum) {
    __shared__ int s[SCAN_B];
    int t = threadIdx.x;
    int i = blockIdx.x * SCAN_B + t;
    s[t] = (i < N_NODES) ? deg[i] : 0;
    __syncthreads();
    for (int off = SCAN_B / 2; off > 0; off >>= 1) {
        if (t < off) s[t] += s[t + off];
        __syncthreads();
    }
    if (t == 0) bsum[blockIdx.x] = s[0];
}

__global__ void k_scan2(int* __restrict__ bsum, int nb, int* __restrict__ ptrN) {
    __shared__ int s[512];
    int t = threadIdx.x;
    int v = (t < nb) ? bsum[t] : 0;
    s[t] = v;
    __syncthreads();
    for (int off = 1; off < 512; off <<= 1) {
        int u = (t >= off) ? s[t - off] : 0;
        __syncthreads();
        s[t] += u;
        __syncthreads();
    }
    if (t < nb) bsum[t] = s[t] - v;          // exclusive block offset
    if (t == nb - 1) *ptrN = s[t];           // total = ptr[N_NODES]
}

__global__ void k_scan3(const int* __restrict__ deg, const int* __restrict__ bsum,
                        int* __restrict__ ptr) {
    __shared__ int s[SCAN_B];
    int t = threadIdx.x;
    int i = blockIdx.x * SCAN_B + t;
    int v = (i < N_NODES) ? deg[i] : 0;
    s[t] = v;
    __syncthreads();
    for (int off = 1; off < SCAN_B; off <<= 1) {
        int u = (t >= off) ? s[t - off] : 0;
        __syncthreads();
        s[t] += u;
        __syncthreads();
    }
    if (i < N_NODES) ptr[i] = bsum[blockIdx.x] + s[t] - v;  // exclusive
}

// ---------------- CSR bucket fill: fused 8B edge record {src, norm} ----------------
__global__ void k_fill(const int* __restrict__ src, const int* __restrict__ dst,
                       const int* __restrict__ deg, const int* __restrict__ ptr,
                       int* __restrict__ fill, int2* __restrict__ edges) {
    int i = blockIdx.x * blockDim.x + threadIdx.x;
    if (i < N_EDGES) {
        int s = src[i], d = dst[i];
        int ds = deg[s], dd = deg[d];
        float ns = (ds > 0) ? rsqrtf((float)ds) : 0.0f;
        float nd = (dd > 0) ? rsqrtf((float)dd) : 0.0f;
        int pos = ptr[d] + atomicAdd(&fill[d], 1);
        edges[pos] = make_int2(s, __float_as_int(ns * nd));
    }
}

// ---------------- node feature init: x = [emb || relu(sf @ pw + pb)] ----------------
__global__ void k_node_init(const float* __restrict__ emb, const float* __restrict__ sfeat,
                            const float* __restrict__ pw, const float* __restrict__ pb,
                            float* __restrict__ x) {
    int idx = blockIdx.x * blockDim.x + threadIdx.x;
    if (idx >= N_NODES * HIDDEN) return;
    int n = idx >> 7, c = idx & 127;
    float v;
    if (c < EMB_DIM) {
        v = emb[n * EMB_DIM + c];
    } else {
        int j = c - EMB_DIM;
        float a = pb[j];
        #pragma unroll
        for (int k = 0; k < NSTRUCT; ++k) a += sfeat[n * NSTRUCT + k] * pw[k * NSTRUCT + j];
        v = fmaxf(a, 0.0f);
    }
    x[idx] = v;
}

// ---------------- GEMM: h = x @ W, fp16 output ----------------
__global__ __launch_bounds__(256, 3)
void k_gemm(const float* __restrict__ x, const float* __restrict__ W,
            __half* __restrict__ h) {
    __shared__ float Ws[64 * HIDDEN];   // 32 KB
    __shared__ float xs[64][65];        // 16.6 KB padded

    const int tid = threadIdx.x;
    const int n0  = blockIdx.x * 64;
    const int cg  = tid & 15;
    const int rg  = tid >> 4;
    const int c0  = cg * 4;
    const int r0  = rg * 4;

    float acc[4][8];
    #pragma unroll
    for (int i = 0; i < 4; ++i)
        #pragma unroll
        for (int j = 0; j < 8; ++j) acc[i][j] = 0.0f;

    for (int kk = 0; kk < HIDDEN; kk += 64) {
        for (int i = tid; i < 64 * HIDDEN; i += 256) Ws[i] = W[kk * HIDDEN + i];
        for (int i = tid; i < 64 * 64; i += 256) {
            int r = i >> 6, k = i & 63;
            int gn = n0 + r;
            xs[r][k] = (gn < N_NODES) ? x[(size_t)gn * HIDDEN + kk + k] : 0.0f;
        }
        __syncthreads();

        #pragma unroll 4
        for (int k = 0; k < 64; ++k) {
            float4 wa = *reinterpret_cast<const float4*>(&Ws[k * HIDDEN + c0]);
            float4 wb = *reinterpret_cast<const float4*>(&Ws[k * HIDDEN + c0 + 64]);
            #pragma unroll
            for (int i = 0; i < 4; ++i) {
                float xv = xs[r0 + i][k];
                acc[i][0] = fmaf(xv, wa.x, acc[i][0]);
                acc[i][1] = fmaf(xv, wa.y, acc[i][1]);
                acc[i][2] = fmaf(xv, wa.z, acc[i][2]);
                acc[i][3] = fmaf(xv, wa.w, acc[i][3]);
                acc[i][4] = fmaf(xv, wb.x, acc[i][4]);
                acc[i][5] = fmaf(xv, wb.y, acc[i][5]);
                acc[i][6] = fmaf(xv, wb.z, acc[i][6]);
                acc[i][7] = fmaf(xv, wb.w, acc[i][7]);
            }
        }
        __syncthreads();
    }

    #pragma unroll
    for (int i = 0; i < 4; ++i) {
        int gn = n0 + r0 + i;
        if (gn < N_NODES) {
            union { uint2 u; __half2 h2[2]; } p0, p1;
            p0.h2[0] = __floats2half2_rn(acc[i][0], acc[i][1]);
            p0.h2[1] = __floats2half2_rn(acc[i][2], acc[i][3]);
            p1.h2[0] = __floats2half2_rn(acc[i][4], acc[i][5]);
            p1.h2[1] = __floats2half2_rn(acc[i][6], acc[i][7]);
            *reinterpret_cast<uint2*>(&h[(size_t)gn * HIDDEN + c0])      = p0.u;
            *reinterpret_cast<uint2*>(&h[(size_t)gn * HIDDEN + c0 + 64]) = p1.u;
        }
    }
}

// ---------------- aggregation + fused bias/BN/ReLU/residual ----------------
// One wave per node, h in fp16. Lane quarter q=lane>>4 handles edge jj+q;
// sl=lane&15 owns cols 8*sl..8*sl+7 (16B uint4 load). One wave instruction
// gathers FOUR h rows (4 x 256B = 1KB). Branchless tail: lanes past the edge
// count carry rec=(0,0) so norm=0. Cross-quarter __shfl_xor(16/32) reduce.
__global__ __launch_bounds__(256)
void k_agg(const __half* __restrict__ h, const int* __restrict__ ptr,
           const int2* __restrict__ edges,
           const float* __restrict__ bias, const float* __restrict__ mean,
           const float* __restrict__ var, const float* __restrict__ gamma,
           const float* __restrict__ beta,
           const float* __restrict__ xprev, int has_resid,
           float* __restrict__ out) {
    int node = blockIdx.x * 4 + (threadIdx.x >> 6);
    if (node >= N_NODES) return;
    const int lane = threadIdx.x & 63;
    const int q    = lane >> 4;
    const int sl   = lane & 15;
    const int c0   = sl * 8;
    int s = ptr[node], e = ptr[node + 1];

    float acc[8];
    #pragma unroll
    for (int k = 0; k < 8; ++k) acc[k] = 0.0f;

    for (int j0 = s; j0 < e; j0 += 64) {
        int nb  = min(64, e - j0);
        int idx = j0 + lane;
        int2 rec = (idx < e) ? edges[idx] : make_int2(0, 0);
        #pragma unroll 2
        for (int jj = 0; jj < nb; jj += 4) {
            int   sv = __shfl(rec.x, jj + q);
            float nv = __int_as_float(__shfl(rec.y, jj + q));
            union { uint4 u; __half2 h2[4]; } v;
            v.u = *reinterpret_cast<const uint4*>(h + ((size_t)sv << 7) + c0);
            #pragma unroll
            for (int k = 0; k < 4; ++k) {
                float2 f = __half22float2(v.h2[k]);
                acc[2 * k]     = fmaf(nv, f.x, acc[2 * k]);
                acc[2 * k + 1] = fmaf(nv, f.y, acc[2 * k + 1]);
            }
        }
    }

    #pragma unroll
    for (int k = 0; k < 8; ++k) {
        acc[k] += __shfl_xor(acc[k], 16);
        acc[k] += __shfl_xor(acc[k], 32);
    }

    if (q == 0) {
        float4 bi0 = *reinterpret_cast<const float4*>(bias  + c0);
        float4 bi1 = *reinterpret_cast<const float4*>(bias  + c0 + 4);
        float4 mu0 = *reinterpret_cast<const float4*>(mean  + c0);
        float4 mu1 = *reinterpret_cast<const float4*>(mean  + c0 + 4);
        float4 va0 = *reinterpret_cast<const float4*>(var   + c0);
        float4 va1 = *reinterpret_cast<const float4*>(var   + c0 + 4);
        float4 ga0 = *reinterpret_cast<const float4*>(gamma + c0);
        float4 ga1 = *reinterpret_cast<const float4*>(gamma + c0 + 4);
        float4 be0 = *reinterpret_cast<const float4*>(beta  + c0);
        float4 be1 = *reinterpret_cast<const float4*>(beta  + c0 + 4);
        float4 y0, y1;
        y0.x = fmaxf((acc[0] + bi0.x - mu0.x) * (ga0.x * rsqrtf(va0.x + BN_EPS)) + be0.x, 0.0f);
        y0.y = fmaxf((acc[1] + bi0.y - mu0.y) * (ga0.y * rsqrtf(va0.y + BN_EPS)) + be0.y, 0.0f);
        y0.z = fmaxf((acc[2] + bi0.z - mu0.z) * (ga0.z * rsqrtf(va0.z + BN_EPS)) + be0.z, 0.0f);
        y0.w = fmaxf((acc[3] + bi0.w - mu0.w) * (ga0.w * rsqrtf(va0.w + BN_EPS)) + be0.w, 0.0f);
        y1.x = fmaxf((acc[4] + bi1.x - mu1.x) * (ga1.x * rsqrtf(va1.x + BN_EPS)) + be1.x, 0.0f);
        y1.y = fmaxf((acc[5] + bi1.y - mu1.y) * (ga1.y * rsqrtf(va1.y + BN_EPS)) + be1.y, 0.0f);
        y1.z = fmaxf((acc[6] + bi1.z - mu1.z) * (ga1.z * rsqrtf(va1.z + BN_EPS)) + be1.z, 0.0f);
        y1.w = fmaxf((acc[7] + bi1.w - mu1.w) * (ga1.w * rsqrtf(va1.w + BN_EPS)) + be1.w, 0.0f);
        size_t o = ((size_t)node << 7) + c0;
        if (has_resid) {
            float4 xp0 = *reinterpret_cast<const float4*>(xprev + o);
            float4 xp1 = *reinterpret_cast<const float4*>(xprev + o + 4);
            y0.x += 0.5f * xp0.x;  y0.y += 0.5f * xp0.y;
            y0.z += 0.5f * xp0.z;  y0.w += 0.5f * xp0.w;
            y1.x += 0.5f * xp1.x;  y1.y += 0.5f * xp1.y;
            y1.z += 0.5f * xp1.z;  y1.w += 0.5f * xp1.w;
        }
        *reinterpret_cast<float4*>(out + o)     = y0;
        *reinterpret_cast<float4*>(out + o + 4) = y1;
    }
}

// ---------------- launch ----------------
extern "C" void kernel_launch(void* const* d_in, const int* in_sizes, int n_in,
                              void* d_out, int out_size, void* d_ws, size_t ws_size,
                              hipStream_t stream) {
    const int*   ei    = (const int*)d_in[0];
    const int*   src   = ei;
    const int*   dst   = ei + N_EDGES;
    const float* sfeat = (const float*)d_in[1];
    const float* emb   = (const float*)d_in[2];
    const float* pw    = (const float*)d_in[3];
    const float* pb    = (const float*)d_in[4];
    const float* convw = (const float*)d_in[5];
    const float* convb = (const float*)d_in[6];
    const float* gamma = (const float*)d_in[7];
    const float* beta  = (const float*)d_in[8];
    const float* mean  = (const float*)d_in[9];
    const float* var   = (const float*)d_in[10];
    float* out = (float*)d_out;

    char* wsc = (char*)d_ws;
    auto alloc = [&](size_t bytes) -> void* {
        void* p = (void*)wsc;
        wsc += (bytes + 255) & ~(size_t)255;
        return p;
    };
    int*    deg   = (int*)   alloc(N_NODES * sizeof(int));
    int*    fill  = (int*)   alloc(N_NODES * sizeof(int));
    int*    ptr   = (int*)   alloc((N_NODES + 1) * sizeof(int));
    int*    bsum  = (int*)   alloc(512 * sizeof(int));
    int2*   edges = (int2*)  alloc((size_t)N_EDGES * sizeof(int2));
    float*  bufA  = (float*) alloc((size_t)N_NODES * HIDDEN * sizeof(float));
    __half* hbuf  = (__half*)alloc((size_t)N_NODES * HIDDEN * sizeof(__half));

    const int nb = (N_NODES + SCAN_B - 1) / SCAN_B;   // 391

    hipMemsetAsync(deg,  0, N_NODES * sizeof(int), stream);
    hipMemsetAsync(fill, 0, N_NODES * sizeof(int), stream);

    k_count_deg<<<N_EDGES / 256, 256, 0, stream>>>(dst, deg);
    k_scan1<<<nb, SCAN_B, 0, stream>>>(deg, bsum);
    k_scan2<<<1, 512, 0, stream>>>(bsum, nb, &ptr[N_NODES]);
    k_scan3<<<nb, SCAN_B, 0, stream>>>(deg, bsum, ptr);
    k_fill<<<N_EDGES / 256, 256, 0, stream>>>(src, dst, deg, ptr, fill, edges);
    k_node_init<<<(N_NODES * HIDDEN) / 256, 256, 0, stream>>>(emb, sfeat, pw, pb, bufA);

    const int ggrid = (N_NODES + 63) / 64;     // 1563
    const int agrid = (N_NODES + 3) / 4;       // 25000

    // layer 0: x1 <- bufA (no residual)
    k_gemm<<<ggrid, 256, 0, stream>>>(bufA, convw + 0 * HIDDEN * HIDDEN, hbuf);
    k_agg<<<agrid, 256, 0, stream>>>(hbuf, ptr, edges,
                                     convb + 0 * HIDDEN, mean + 0 * HIDDEN, var + 0 * HIDDEN,
                                     gamma + 0 * HIDDEN, beta + 0 * HIDDEN,
                                     nullptr, 0, bufA);
    // layer 1: x2 <- out (residual 0.5*x1)
    k_gemm<<<ggrid, 256, 0, stream>>>(bufA, convw + 1 * HIDDEN * HIDDEN, hbuf);
    k_agg<<<agrid, 256, 0, stream>>>(hbuf, ptr, edges,
                                     convb + 1 * HIDDEN, mean + 1 * HIDDEN, var + 1 * HIDDEN,
                                     gamma + 1 * HIDDEN, beta + 1 * HIDDEN,
                                     bufA, 1, out);
    // layer 2: final <- out (residual 0.5*x2)
    k_gemm<<<ggrid, 256, 0, stream>>>(out, convw + 2 * HIDDEN * HIDDEN, hbuf);
    k_agg<<<agrid, 256, 0, stream>>>(hbuf, ptr, edges,
                                     convb + 2 * HIDDEN, mean + 2 * HIDDEN, var + 2 * HIDDEN,
                                     gamma + 2 * HIDDEN, beta + 2 * HIDDEN,
                                     out, 1, out);
    (void)in_sizes; (void)n_in; (void)out_size; (void)ws_size;
}

// Round 9
// 667.122 us; speedup vs baseline: 1.3170x; 1.0674x over previous
//
#include <hip/hip_runtime.h>
#include <hip/hip_fp16.h>

#define N_NODES 100000
#define N_EDGES 1600000
#define HIDDEN  128
#define EMB_DIM 122       // HIDDEN - N_STRUCT
#define NSTRUCT 6
#define BN_EPS  1e-5f

// ---------------- degree count (dst side) + per-edge rank ----------------
// rank[i] = position of edge i within its dst bucket (atomic return is free).
__global__ void k_count_deg(const int* __restrict__ dst, int* __restrict__ deg,
                            int* __restrict__ rank) {
    int i = blockIdx.x * blockDim.x + threadIdx.x;
    if (i < N_EDGES) rank[i] = atomicAdd(&deg[dst[i]], 1);
}

// ---------------- exclusive scan of deg -> ptr ----------------
#define SCAN_B 256
__global__ void k_scan1(const int* __restrict__ deg, int* __restrict__ bsum) {
    __shared__ int s[SCAN_B];
    int t = threadIdx.x;
    int i = blockIdx.x * SCAN_B + t;
    s[t] = (i < N_NODES) ? deg[i] : 0;
    __syncthreads();
    for (int off = SCAN_B / 2; off > 0; off >>= 1) {
        if (t < off) s[t] += s[t + off];
        __syncthreads();
    }
    if (t == 0) bsum[blockIdx.x] = s[0];
}

__global__ void k_scan2(int* __restrict__ bsum, int nb, int* __restrict__ ptrN) {
    __shared__ int s[512];
    int t = threadIdx.x;
    int v = (t < nb) ? bsum[t] : 0;
    s[t] = v;
    __syncthreads();
    for (int off = 1; off < 512; off <<= 1) {
        int u = (t >= off) ? s[t - off] : 0;
        __syncthreads();
        s[t] += u;
        __syncthreads();
    }
    if (t < nb) bsum[t] = s[t] - v;          // exclusive block offset
    if (t == nb - 1) *ptrN = s[t];           // total = ptr[N_NODES]
}

__global__ void k_scan3(const int* __restrict__ deg, const int* __restrict__ bsum,
                        int* __restrict__ ptr) {
    __shared__ int s[SCAN_B];
    int t = threadIdx.x;
    int i = blockIdx.x * SCAN_B + t;
    int v = (i < N_NODES) ? deg[i] : 0;
    s[t] = v;
    __syncthreads();
    for (int off = 1; off < SCAN_B; off <<= 1) {
        int u = (t >= off) ? s[t - off] : 0;
        __syncthreads();
        s[t] += u;
        __syncthreads();
    }
    if (i < N_NODES) ptr[i] = bsum[blockIdx.x] + s[t] - v;  // exclusive
}

// ---------------- CSR fill: NO atomics (pos = ptr[d] + rank[i]) ----------------
__global__ void k_fill(const int* __restrict__ src, const int* __restrict__ dst,
                       const int* __restrict__ rank,
                       const int* __restrict__ deg, const int* __restrict__ ptr,
                       int2* __restrict__ edges) {
    int i = blockIdx.x * blockDim.x + threadIdx.x;
    if (i < N_EDGES) {
        int s = src[i], d = dst[i];
        int ds = deg[s], dd = deg[d];
        float ns = (ds > 0) ? rsqrtf((float)ds) : 0.0f;
        float nd = (dd > 0) ? rsqrtf((float)dd) : 0.0f;
        int pos = ptr[d] + rank[i];
        edges[pos] = make_int2(s, __float_as_int(ns * nd));
    }
}

// ---------------- node feature init: x = [emb || relu(sf @ pw + pb)] ----------------
__global__ void k_node_init(const float* __restrict__ emb, const float* __restrict__ sfeat,
                            const float* __restrict__ pw, const float* __restrict__ pb,
                            float* __restrict__ x) {
    int idx = blockIdx.x * blockDim.x + threadIdx.x;
    if (idx >= N_NODES * HIDDEN) return;
    int n = idx >> 7, c = idx & 127;
    float v;
    if (c < EMB_DIM) {
        v = emb[n * EMB_DIM + c];
    } else {
        int j = c - EMB_DIM;
        float a = pb[j];
        #pragma unroll
        for (int k = 0; k < NSTRUCT; ++k) a += sfeat[n * NSTRUCT + k] * pw[k * NSTRUCT + j];
        v = fmaxf(a, 0.0f);
    }
    x[idx] = v;
}

// ---------------- GEMM: h = x @ W, fp16 output ----------------
__global__ __launch_bounds__(256, 3)
void k_gemm(const float* __restrict__ x, const float* __restrict__ W,
            __half* __restrict__ h) {
    __shared__ float Ws[64 * HIDDEN];   // 32 KB
    __shared__ float xs[64][65];        // 16.6 KB padded

    const int tid = threadIdx.x;
    const int n0  = blockIdx.x * 64;
    const int cg  = tid & 15;
    const int rg  = tid >> 4;
    const int c0  = cg * 4;
    const int r0  = rg * 4;

    float acc[4][8];
    #pragma unroll
    for (int i = 0; i < 4; ++i)
        #pragma unroll
        for (int j = 0; j < 8; ++j) acc[i][j] = 0.0f;

    for (int kk = 0; kk < HIDDEN; kk += 64) {
        for (int i = tid; i < 64 * HIDDEN; i += 256) Ws[i] = W[kk * HIDDEN + i];
        for (int i = tid; i < 64 * 64; i += 256) {
            int r = i >> 6, k = i & 63;
            int gn = n0 + r;
            xs[r][k] = (gn < N_NODES) ? x[(size_t)gn * HIDDEN + kk + k] : 0.0f;
        }
        __syncthreads();

        #pragma unroll 4
        for (int k = 0; k < 64; ++k) {
            float4 wa = *reinterpret_cast<const float4*>(&Ws[k * HIDDEN + c0]);
            float4 wb = *reinterpret_cast<const float4*>(&Ws[k * HIDDEN + c0 + 64]);
            #pragma unroll
            for (int i = 0; i < 4; ++i) {
                float xv = xs[r0 + i][k];
                acc[i][0] = fmaf(xv, wa.x, acc[i][0]);
                acc[i][1] = fmaf(xv, wa.y, acc[i][1]);
                acc[i][2] = fmaf(xv, wa.z, acc[i][2]);
                acc[i][3] = fmaf(xv, wa.w, acc[i][3]);
                acc[i][4] = fmaf(xv, wb.x, acc[i][4]);
                acc[i][5] = fmaf(xv, wb.y, acc[i][5]);
                acc[i][6] = fmaf(xv, wb.z, acc[i][6]);
                acc[i][7] = fmaf(xv, wb.w, acc[i][7]);
            }
        }
        __syncthreads();
    }

    #pragma unroll
    for (int i = 0; i < 4; ++i) {
        int gn = n0 + r0 + i;
        if (gn < N_NODES) {
            union { uint2 u; __half2 h2[2]; } p0, p1;
            p0.h2[0] = __floats2half2_rn(acc[i][0], acc[i][1]);
            p0.h2[1] = __floats2half2_rn(acc[i][2], acc[i][3]);
            p1.h2[0] = __floats2half2_rn(acc[i][4], acc[i][5]);
            p1.h2[1] = __floats2half2_rn(acc[i][6], acc[i][7]);
            *reinterpret_cast<uint2*>(&h[(size_t)gn * HIDDEN + c0])      = p0.u;
            *reinterpret_cast<uint2*>(&h[(size_t)gn * HIDDEN + c0 + 64]) = p1.u;
        }
    }
}

// ---------------- aggregation + fused bias/BN/ReLU/residual ----------------
// One wave per node, h in fp16. Lane quarter q=lane>>4 handles edge jj+q;
// sl=lane&15 owns cols 8*sl..8*sl+7 (16B uint4 load). One wave instruction
// gathers FOUR h rows (4 x 256B = 1KB). Branchless tail: lanes past the edge
// count carry rec=(0,0) so norm=0. Cross-quarter __shfl_xor(16/32) reduce.
__global__ __launch_bounds__(256)
void k_agg(const __half* __restrict__ h, const int* __restrict__ ptr,
           const int2* __restrict__ edges,
           const float* __restrict__ bias, const float* __restrict__ mean,
           const float* __restrict__ var, const float* __restrict__ gamma,
           const float* __restrict__ beta,
           const float* __restrict__ xprev, int has_resid,
           float* __restrict__ out) {
    int node = blockIdx.x * 4 + (threadIdx.x >> 6);
    if (node >= N_NODES) return;
    const int lane = threadIdx.x & 63;
    const int q    = lane >> 4;
    const int sl   = lane & 15;
    const int c0   = sl * 8;
    int s = ptr[node], e = ptr[node + 1];

    float acc[8];
    #pragma unroll
    for (int k = 0; k < 8; ++k) acc[k] = 0.0f;

    for (int j0 = s; j0 < e; j0 += 64) {
        int nb  = min(64, e - j0);
        int idx = j0 + lane;
        int2 rec = (idx < e) ? edges[idx] : make_int2(0, 0);
        #pragma unroll 2
        for (int jj = 0; jj < nb; jj += 4) {
            int   sv = __shfl(rec.x, jj + q);
            float nv = __int_as_float(__shfl(rec.y, jj + q));
            union { uint4 u; __half2 h2[4]; } v;
            v.u = *reinterpret_cast<const uint4*>(h + ((size_t)sv << 7) + c0);
            #pragma unroll
            for (int k = 0; k < 4; ++k) {
                float2 f = __half22float2(v.h2[k]);
                acc[2 * k]     = fmaf(nv, f.x, acc[2 * k]);
                acc[2 * k + 1] = fmaf(nv, f.y, acc[2 * k + 1]);
            }
        }
    }

    #pragma unroll
    for (int k = 0; k < 8; ++k) {
        acc[k] += __shfl_xor(acc[k], 16);
        acc[k] += __shfl_xor(acc[k], 32);
    }

    if (q == 0) {
        float4 bi0 = *reinterpret_cast<const float4*>(bias  + c0);
        float4 bi1 = *reinterpret_cast<const float4*>(bias  + c0 + 4);
        float4 mu0 = *reinterpret_cast<const float4*>(mean  + c0);
        float4 mu1 = *reinterpret_cast<const float4*>(mean  + c0 + 4);
        float4 va0 = *reinterpret_cast<const float4*>(var   + c0);
        float4 va1 = *reinterpret_cast<const float4*>(var   + c0 + 4);
        float4 ga0 = *reinterpret_cast<const float4*>(gamma + c0);
        float4 ga1 = *reinterpret_cast<const float4*>(gamma + c0 + 4);
        float4 be0 = *reinterpret_cast<const float4*>(beta  + c0);
        float4 be1 = *reinterpret_cast<const float4*>(beta  + c0 + 4);
        float4 y0, y1;
        y0.x = fmaxf((acc[0] + bi0.x - mu0.x) * (ga0.x * rsqrtf(va0.x + BN_EPS)) + be0.x, 0.0f);
        y0.y = fmaxf((acc[1] + bi0.y - mu0.y) * (ga0.y * rsqrtf(va0.y + BN_EPS)) + be0.y, 0.0f);
        y0.z = fmaxf((acc[2] + bi0.z - mu0.z) * (ga0.z * rsqrtf(va0.z + BN_EPS)) + be0.z, 0.0f);
        y0.w = fmaxf((acc[3] + bi0.w - mu0.w) * (ga0.w * rsqrtf(va0.w + BN_EPS)) + be0.w, 0.0f);
        y1.x = fmaxf((acc[4] + bi1.x - mu1.x) * (ga1.x * rsqrtf(va1.x + BN_EPS)) + be1.x, 0.0f);
        y1.y = fmaxf((acc[5] + bi1.y - mu1.y) * (ga1.y * rsqrtf(va1.y + BN_EPS)) + be1.y, 0.0f);
        y1.z = fmaxf((acc[6] + bi1.z - mu1.z) * (ga1.z * rsqrtf(va1.z + BN_EPS)) + be1.z, 0.0f);
        y1.w = fmaxf((acc[7] + bi1.w - mu1.w) * (ga1.w * rsqrtf(va1.w + BN_EPS)) + be1.w, 0.0f);
        size_t o = ((size_t)node << 7) + c0;
        if (has_resid) {
            float4 xp0 = *reinterpret_cast<const float4*>(xprev + o);
            float4 xp1 = *reinterpret_cast<const float4*>(xprev + o + 4);
            y0.x += 0.5f * xp0.x;  y0.y += 0.5f * xp0.y;
            y0.z += 0.5f * xp0.z;  y0.w += 0.5f * xp0.w;
            y1.x += 0.5f * xp1.x;  y1.y += 0.5f * xp1.y;
            y1.z += 0.5f * xp1.z;  y1.w += 0.5f * xp1.w;
        }
        *reinterpret_cast<float4*>(out + o)     = y0;
        *reinterpret_cast<float4*>(out + o + 4) = y1;
    }
}

// ---------------- launch ----------------
extern "C" void kernel_launch(void* const* d_in, const int* in_sizes, int n_in,
                              void* d_out, int out_size, void* d_ws, size_t ws_size,
                              hipStream_t stream) {
    const int*   ei    = (const int*)d_in[0];
    const int*   src   = ei;
    const int*   dst   = ei + N_EDGES;
    const float* sfeat = (const float*)d_in[1];
    const float* emb   = (const float*)d_in[2];
    const float* pw    = (const float*)d_in[3];
    const float* pb    = (const float*)d_in[4];
    const float* convw = (const float*)d_in[5];
    const float* convb = (const float*)d_in[6];
    const float* gamma = (const float*)d_in[7];
    const float* beta  = (const float*)d_in[8];
    const float* mean  = (const float*)d_in[9];
    const float* var   = (const float*)d_in[10];
    float* out = (float*)d_out;

    char* wsc = (char*)d_ws;
    auto alloc = [&](size_t bytes) -> void* {
        void* p = (void*)wsc;
        wsc += (bytes + 255) & ~(size_t)255;
        return p;
    };
    int*    deg   = (int*)   alloc(N_NODES * sizeof(int));
    int*    rank  = (int*)   alloc((size_t)N_EDGES * sizeof(int));
    int*    ptr   = (int*)   alloc((N_NODES + 1) * sizeof(int));
    int*    bsum  = (int*)   alloc(512 * sizeof(int));
    int2*   edges = (int2*)  alloc((size_t)N_EDGES * sizeof(int2));
    float*  bufA  = (float*) alloc((size_t)N_NODES * HIDDEN * sizeof(float));
    __half* hbuf  = (__half*)alloc((size_t)N_NODES * HIDDEN * sizeof(__half));

    const int nb = (N_NODES + SCAN_B - 1) / SCAN_B;   // 391

    hipMemsetAsync(deg, 0, N_NODES * sizeof(int), stream);

    k_count_deg<<<N_EDGES / 256, 256, 0, stream>>>(dst, deg, rank);
    k_scan1<<<nb, SCAN_B, 0, stream>>>(deg, bsum);
    k_scan2<<<1, 512, 0, stream>>>(bsum, nb, &ptr[N_NODES]);
    k_scan3<<<nb, SCAN_B, 0, stream>>>(deg, bsum, ptr);
    k_fill<<<N_EDGES / 256, 256, 0, stream>>>(src, dst, rank, deg, ptr, edges);
    k_node_init<<<(N_NODES * HIDDEN) / 256, 256, 0, stream>>>(emb, sfeat, pw, pb, bufA);

    const int ggrid = (N_NODES + 63) / 64;     // 1563
    const int agrid = (N_NODES + 3) / 4;       // 25000

    // layer 0: x1 <- bufA (no residual)
    k_gemm<<<ggrid, 256, 0, stream>>>(bufA, convw + 0 * HIDDEN * HIDDEN, hbuf);
    k_agg<<<agrid, 256, 0, stream>>>(hbuf, ptr, edges,
                                     convb + 0 * HIDDEN, mean + 0 * HIDDEN, var + 0 * HIDDEN,
                                     gamma + 0 * HIDDEN, beta + 0 * HIDDEN,
                                     nullptr, 0, bufA);
    // layer 1: x2 <- out (residual 0.5*x1)
    k_gemm<<<ggrid, 256, 0, stream>>>(bufA, convw + 1 * HIDDEN * HIDDEN, hbuf);
    k_agg<<<agrid, 256, 0, stream>>>(hbuf, ptr, edges,
                                     convb + 1 * HIDDEN, mean + 1 * HIDDEN, var + 1 * HIDDEN,
                                     gamma + 1 * HIDDEN, beta + 1 * HIDDEN,
                                     bufA, 1, out);
    // layer 2: final <- out (residual 0.5*x2)
    k_gemm<<<ggrid, 256, 0, stream>>>(out, convw + 2 * HIDDEN * HIDDEN, hbuf);
    k_agg<<<agrid, 256, 0, stream>>>(hbuf, ptr, edges,
                                     convb + 2 * HIDDEN, mean + 2 * HIDDEN, var + 2 * HIDDEN,
                                     gamma + 2 * HIDDEN, beta + 2 * HIDDEN,
                                     out, 1, out);
    (void)in_sizes; (void)n_in; (void)out_size; (void)ws_size;
}

// Round 11
// 608.330 us; speedup vs baseline: 1.4443x; 1.0966x over previous
//
#include <hip/hip_runtime.h>
#include <hip/hip_fp16.h>

#define N_NODES 100000
#define N_EDGES 1600000
#define HIDDEN  128
#define EMB_DIM 122       // HIDDEN - N_STRUCT
#define NSTRUCT 6
#define BN_EPS  1e-5f

typedef _Float16 f16x8 __attribute__((ext_vector_type(8)));
typedef float    f32x4 __attribute__((ext_vector_type(4)));

// ---------------- degree count (dst side) + per-edge rank ----------------
__global__ void k_count_deg(const int* __restrict__ dst, int* __restrict__ deg,
                            int* __restrict__ rank) {
    int i = blockIdx.x * blockDim.x + threadIdx.x;
    if (i < N_EDGES) rank[i] = atomicAdd(&deg[dst[i]], 1);
}

// ---------------- exclusive scan of deg -> ptr ----------------
#define SCAN_B 256
__global__ void k_scan1(const int* __restrict__ deg, int* __restrict__ bsum) {
    __shared__ int s[SCAN_B];
    int t = threadIdx.x;
    int i = blockIdx.x * SCAN_B + t;
    s[t] = (i < N_NODES) ? deg[i] : 0;
    __syncthreads();
    for (int off = SCAN_B / 2; off > 0; off >>= 1) {
        if (t < off) s[t] += s[t + off];
        __syncthreads();
    }
    if (t == 0) bsum[blockIdx.x] = s[0];
}

__global__ void k_scan2(int* __restrict__ bsum, int nb, int* __restrict__ ptrN) {
    __shared__ int s[512];
    int t = threadIdx.x;
    int v = (t < nb) ? bsum[t] : 0;
    s[t] = v;
    __syncthreads();
    for (int off = 1; off < 512; off <<= 1) {
        int u = (t >= off) ? s[t - off] : 0;
        __syncthreads();
        s[t] += u;
        __syncthreads();
    }
    if (t < nb) bsum[t] = s[t] - v;          // exclusive block offset
    if (t == nb - 1) *ptrN = s[t];           // total = ptr[N_NODES]
}

__global__ void k_scan3(const int* __restrict__ deg, const int* __restrict__ bsum,
                        int* __restrict__ ptr) {
    __shared__ int s[SCAN_B];
    int t = threadIdx.x;
    int i = blockIdx.x * SCAN_B + t;
    int v = (i < N_NODES) ? deg[i] : 0;
    s[t] = v;
    __syncthreads();
    for (int off = 1; off < SCAN_B; off <<= 1) {
        int u = (t >= off) ? s[t - off] : 0;
        __syncthreads();
        s[t] += u;
        __syncthreads();
    }
    if (i < N_NODES) ptr[i] = bsum[blockIdx.x] + s[t] - v;  // exclusive
}

// ---------------- CSR fill: NO atomics (pos = ptr[d] + rank[i]) ----------------
__global__ void k_fill(const int* __restrict__ src, const int* __restrict__ dst,
                       const int* __restrict__ rank,
                       const int* __restrict__ deg, const int* __restrict__ ptr,
                       int2* __restrict__ edges) {
    int i = blockIdx.x * blockDim.x + threadIdx.x;
    if (i < N_EDGES) {
        int s = src[i], d = dst[i];
        int ds = deg[s], dd = deg[d];
        float ns = (ds > 0) ? rsqrtf((float)ds) : 0.0f;
        float nd = (dd > 0) ? rsqrtf((float)dd) : 0.0f;
        int pos = ptr[d] + rank[i];
        edges[pos] = make_int2(s, __float_as_int(ns * nd));
    }
}

// ---------------- node feature init: x = [emb || relu(sf @ pw + pb)] ----------------
__global__ void k_node_init(const float* __restrict__ emb, const float* __restrict__ sfeat,
                            const float* __restrict__ pw, const float* __restrict__ pb,
                            float* __restrict__ x) {
    int idx = blockIdx.x * blockDim.x + threadIdx.x;
    if (idx >= N_NODES * HIDDEN) return;
    int n = idx >> 7, c = idx & 127;
    float v;
    if (c < EMB_DIM) {
        v = emb[n * EMB_DIM + c];
    } else {
        int j = c - EMB_DIM;
        float a = pb[j];
        #pragma unroll
        for (int k = 0; k < NSTRUCT; ++k) a += sfeat[n * NSTRUCT + k] * pw[k * NSTRUCT + j];
        v = fmaxf(a, 0.0f);
    }
    x[idx] = v;
}

// ---------------- W transpose+cvt: Wt[l][n][k] = (half)W[l][k][n] ----------------
__global__ void k_wcvt(const float* __restrict__ W, __half* __restrict__ Wt) {
    int idx = blockIdx.x * blockDim.x + threadIdx.x;       // 3*128*128
    int l = idx >> 14, rem = idx & 16383, n = rem >> 7, k = rem & 127;
    Wt[idx] = __float2half(W[l * 16384 + k * 128 + n]);
}

// ---------------- MFMA GEMM: h = (half)(x @ W), fp32 accumulate ----------------
// Block 256 thr = 4 waves; block tile 64 rows; wave tile 16 rows x 128 cols.
// A-frag: lane&15 = row m, k = kc*32 + (lane>>4)*8 + i  (direct fp32 global read + cvt)
// B-frag: lane&15 = col n, same k mapping, from Wt[n][k] fp16 (L2-hot, 64B/row segments)
// C/D: col = lane&15, row = (lane>>4)*4 + reg   [m89-verified mapping]
__global__ __launch_bounds__(256)
void k_gemm(const float* __restrict__ x, const __half* __restrict__ Wt,
            __half* __restrict__ h) {
    const int tid  = threadIdx.x;
    const int w    = tid >> 6;
    const int lane = tid & 63;
    const int g    = lane >> 4;
    const int m15  = lane & 15;

    const int rowA = blockIdx.x * 64 + w * 16 + m15;   // row this lane's A-frag feeds
    const bool rok = (rowA < N_NODES);

    f32x4 acc[8];
    #pragma unroll
    for (int nt = 0; nt < 8; ++nt) acc[nt] = (f32x4){0.f, 0.f, 0.f, 0.f};

    #pragma unroll
    for (int kc = 0; kc < 4; ++kc) {
        const int k0 = kc * 32 + g * 8;
        f16x8 a;
        if (rok) {
            const float4 p0 = *reinterpret_cast<const float4*>(x + (size_t)rowA * HIDDEN + k0);
            const float4 p1 = *reinterpret_cast<const float4*>(x + (size_t)rowA * HIDDEN + k0 + 4);
            a[0] = (_Float16)p0.x; a[1] = (_Float16)p0.y;
            a[2] = (_Float16)p0.z; a[3] = (_Float16)p0.w;
            a[4] = (_Float16)p1.x; a[5] = (_Float16)p1.y;
            a[6] = (_Float16)p1.z; a[7] = (_Float16)p1.w;
        } else {
            a = (f16x8)(_Float16)0;
        }
        #pragma unroll
        for (int nt = 0; nt < 8; ++nt) {
            const int n = nt * 16 + m15;
            f16x8 b = *reinterpret_cast<const f16x8*>(Wt + (size_t)n * HIDDEN + k0);
            acc[nt] = __builtin_amdgcn_mfma_f32_16x16x32_f16(a, b, acc[nt], 0, 0, 0);
        }
    }

    // epilogue: D[row=(g*4+r)][col=nt*16+m15]
    const int growbase = blockIdx.x * 64 + w * 16 + g * 4;
    #pragma unroll
    for (int nt = 0; nt < 8; ++nt) {
        const int col = nt * 16 + m15;
        #pragma unroll
        for (int r = 0; r < 4; ++r) {
            const int grow = growbase + r;
            if (grow < N_NODES)
                h[(size_t)grow * HIDDEN + col] = __float2half(acc[nt][r]);
        }
    }
}

// ---------------- aggregation + fused bias/BN/ReLU/residual ----------------
// One wave per node, h in fp16. Lane quarter q=lane>>4 handles edge jj+q;
// sl=lane&15 owns cols 8*sl..8*sl+7 (16B uint4 load). One wave instruction
// gathers FOUR h rows. Cross-quarter __shfl_xor(16/32) reduce.
__global__ __launch_bounds__(256)
void k_agg(const __half* __restrict__ h, const int* __restrict__ ptr,
           const int2* __restrict__ edges,
           const float* __restrict__ bias, const float* __restrict__ mean,
           const float* __restrict__ var, const float* __restrict__ gamma,
           const float* __restrict__ beta,
           const float* __restrict__ xprev, int has_resid,
           float* __restrict__ out) {
    int node = blockIdx.x * 4 + (threadIdx.x >> 6);
    if (node >= N_NODES) return;
    const int lane = threadIdx.x & 63;
    const int q    = lane >> 4;
    const int sl   = lane & 15;
    const int c0   = sl * 8;
    int s = ptr[node], e = ptr[node + 1];

    float acc[8];
    #pragma unroll
    for (int k = 0; k < 8; ++k) acc[k] = 0.0f;

    for (int j0 = s; j0 < e; j0 += 64) {
        int nb  = min(64, e - j0);
        int idx = j0 + lane;
        int2 rec = (idx < e) ? edges[idx] : make_int2(0, 0);
        #pragma unroll 2
        for (int jj = 0; jj < nb; jj += 4) {
            int   sv = __shfl(rec.x, jj + q);
            float nv = __int_as_float(__shfl(rec.y, jj + q));
            union { uint4 u; __half2 h2[4]; } v;
            v.u = *reinterpret_cast<const uint4*>(h + ((size_t)sv << 7) + c0);
            #pragma unroll
            for (int k = 0; k < 4; ++k) {
                float2 f = __half22float2(v.h2[k]);
                acc[2 * k]     = fmaf(nv, f.x, acc[2 * k]);
                acc[2 * k + 1] = fmaf(nv, f.y, acc[2 * k + 1]);
            }
        }
    }

    #pragma unroll
    for (int k = 0; k < 8; ++k) {
        acc[k] += __shfl_xor(acc[k], 16);
        acc[k] += __shfl_xor(acc[k], 32);
    }

    if (q == 0) {
        float4 bi0 = *reinterpret_cast<const float4*>(bias  + c0);
        float4 bi1 = *reinterpret_cast<const float4*>(bias  + c0 + 4);
        float4 mu0 = *reinterpret_cast<const float4*>(mean  + c0);
        float4 mu1 = *reinterpret_cast<const float4*>(mean  + c0 + 4);
        float4 va0 = *reinterpret_cast<const float4*>(var   + c0);
        float4 va1 = *reinterpret_cast<const float4*>(var   + c0 + 4);
        float4 ga0 = *reinterpret_cast<const float4*>(gamma + c0);
        float4 ga1 = *reinterpret_cast<const float4*>(gamma + c0 + 4);
        float4 be0 = *reinterpret_cast<const float4*>(beta  + c0);
        float4 be1 = *reinterpret_cast<const float4*>(beta  + c0 + 4);
        float4 y0, y1;
        y0.x = fmaxf((acc[0] + bi0.x - mu0.x) * (ga0.x * rsqrtf(va0.x + BN_EPS)) + be0.x, 0.0f);
        y0.y = fmaxf((acc[1] + bi0.y - mu0.y) * (ga0.y * rsqrtf(va0.y + BN_EPS)) + be0.y, 0.0f);
        y0.z = fmaxf((acc[2] + bi0.z - mu0.z) * (ga0.z * rsqrtf(va0.z + BN_EPS)) + be0.z, 0.0f);
        y0.w = fmaxf((acc[3] + bi0.w - mu0.w) * (ga0.w * rsqrtf(va0.w + BN_EPS)) + be0.w, 0.0f);
        y1.x = fmaxf((acc[4] + bi1.x - mu1.x) * (ga1.x * rsqrtf(va1.x + BN_EPS)) + be1.x, 0.0f);
        y1.y = fmaxf((acc[5] + bi1.y - mu1.y) * (ga1.y * rsqrtf(va1.y + BN_EPS)) + be1.y, 0.0f);
        y1.z = fmaxf((acc[6] + bi1.z - mu1.z) * (ga1.z * rsqrtf(va1.z + BN_EPS)) + be1.z, 0.0f);
        y1.w = fmaxf((acc[7] + bi1.w - mu1.w) * (ga1.w * rsqrtf(va1.w + BN_EPS)) + be1.w, 0.0f);
        size_t o = ((size_t)node << 7) + c0;
        if (has_resid) {
            float4 xp0 = *reinterpret_cast<const float4*>(xprev + o);
            float4 xp1 = *reinterpret_cast<const float4*>(xprev + o + 4);
            y0.x += 0.5f * xp0.x;  y0.y += 0.5f * xp0.y;
            y0.z += 0.5f * xp0.z;  y0.w += 0.5f * xp0.w;
            y1.x += 0.5f * xp1.x;  y1.y += 0.5f * xp1.y;
            y1.z += 0.5f * xp1.z;  y1.w += 0.5f * xp1.w;
        }
        *reinterpret_cast<float4*>(out + o)     = y0;
        *reinterpret_cast<float4*>(out + o + 4) = y1;
    }
}

// ---------------- launch ----------------
extern "C" void kernel_launch(void* const* d_in, const int* in_sizes, int n_in,
                              void* d_out, int out_size, void* d_ws, size_t ws_size,
                              hipStream_t stream) {
    const int*   ei    = (const int*)d_in[0];
    const int*   src   = ei;
    const int*   dst   = ei + N_EDGES;
    const float* sfeat = (const float*)d_in[1];
    const float* emb   = (const float*)d_in[2];
    const float* pw    = (const float*)d_in[3];
    const float* pb    = (const float*)d_in[4];
    const float* convw = (const float*)d_in[5];
    const float* convb = (const float*)d_in[6];
    const float* gamma = (const float*)d_in[7];
    const float* beta  = (const float*)d_in[8];
    const float* mean  = (const float*)d_in[9];
    const float* var   = (const float*)d_in[10];
    float* out = (float*)d_out;

    char* wsc = (char*)d_ws;
    auto alloc = [&](size_t bytes) -> void* {
        void* p = (void*)wsc;
        wsc += (bytes + 255) & ~(size_t)255;
        return p;
    };
    int*    deg   = (int*)   alloc(N_NODES * sizeof(int));
    int*    rank  = (int*)   alloc((size_t)N_EDGES * sizeof(int));
    int*    ptr   = (int*)   alloc((N_NODES + 1) * sizeof(int));
    int*    bsum  = (int*)   alloc(512 * sizeof(int));
    int2*   edges = (int2*)  alloc((size_t)N_EDGES * sizeof(int2));
    float*  bufA  = (float*) alloc((size_t)N_NODES * HIDDEN * sizeof(float));
    __half* hbuf  = (__half*)alloc((size_t)N_NODES * HIDDEN * sizeof(__half));
    __half* wt    = (__half*)alloc(3 * HIDDEN * HIDDEN * sizeof(__half));

    const int nb = (N_NODES + SCAN_B - 1) / SCAN_B;   // 391

    hipMemsetAsync(deg, 0, N_NODES * sizeof(int), stream);

    k_count_deg<<<N_EDGES / 256, 256, 0, stream>>>(dst, deg, rank);
    k_wcvt<<<(3 * HIDDEN * HIDDEN) / 256, 256, 0, stream>>>(convw, wt);
    k_scan1<<<nb, SCAN_B, 0, stream>>>(deg, bsum);
    k_scan2<<<1, 512, 0, stream>>>(bsum, nb, &ptr[N_NODES]);
    k_scan3<<<nb, SCAN_B, 0, stream>>>(deg, bsum, ptr);
    k_fill<<<N_EDGES / 256, 256, 0, stream>>>(src, dst, rank, deg, ptr, edges);
    k_node_init<<<(N_NODES * HIDDEN) / 256, 256, 0, stream>>>(emb, sfeat, pw, pb, bufA);

    const int ggrid = (N_NODES + 63) / 64;     // 1563
    const int agrid = (N_NODES + 3) / 4;       // 25000

    // layer 0: x1 <- bufA (no residual)
    k_gemm<<<ggrid, 256, 0, stream>>>(bufA, wt + 0 * HIDDEN * HIDDEN, hbuf);
    k_agg<<<agrid, 256, 0, stream>>>(hbuf, ptr, edges,
                                     convb + 0 * HIDDEN, mean + 0 * HIDDEN, var + 0 * HIDDEN,
                                     gamma + 0 * HIDDEN, beta + 0 * HIDDEN,
                                     nullptr, 0, bufA);
    // layer 1: x2 <- out (residual 0.5*x1)
    k_gemm<<<ggrid, 256, 0, stream>>>(bufA, wt + 1 * HIDDEN * HIDDEN, hbuf);
    k_agg<<<agrid, 256, 0, stream>>>(hbuf, ptr, edges,
                                     convb + 1 * HIDDEN, mean + 1 * HIDDEN, var + 1 * HIDDEN,
                                     gamma + 1 * HIDDEN, beta + 1 * HIDDEN,
                                     bufA, 1, out);
    // layer 2: final <- out (residual 0.5*x2)
    k_gemm<<<ggrid, 256, 0, stream>>>(out, wt + 2 * HIDDEN * HIDDEN, hbuf);
    k_agg<<<agrid, 256, 0, stream>>>(hbuf, ptr, edges,
                                     convb + 2 * HIDDEN, mean + 2 * HIDDEN, var + 2 * HIDDEN,
                                     gamma + 2 * HIDDEN, beta + 2 * HIDDEN,
                                     out, 1, out);
    (void)in_sizes; (void)n_in; (void)out_size; (void)ws_size;
}

// Round 12
// 561.375 us; speedup vs baseline: 1.5651x; 1.0836x over previous
//
#include <hip/hip_runtime.h>
#include <hip/hip_fp16.h>

#define N_NODES 100000
#define N_EDGES 1600000
#define HIDDEN  128
#define EMB_DIM 122       // HIDDEN - N_STRUCT
#define NSTRUCT 6
#define BN_EPS  1e-5f

typedef _Float16 f16x8 __attribute__((ext_vector_type(8)));
typedef float    f32x4 __attribute__((ext_vector_type(4)));

// ---------------- degree count (dst side) + per-edge rank ----------------
__global__ void k_count_deg(const int* __restrict__ dst, int* __restrict__ deg,
                            int* __restrict__ rank) {
    int i = blockIdx.x * blockDim.x + threadIdx.x;
    if (i < N_EDGES) rank[i] = atomicAdd(&deg[dst[i]], 1);
}

// ---------------- exclusive scan of deg -> ptr ----------------
#define SCAN_B 256
__global__ void k_scan1(const int* __restrict__ deg, int* __restrict__ bsum) {
    __shared__ int s[SCAN_B];
    int t = threadIdx.x;
    int i = blockIdx.x * SCAN_B + t;
    s[t] = (i < N_NODES) ? deg[i] : 0;
    __syncthreads();
    for (int off = SCAN_B / 2; off > 0; off >>= 1) {
        if (t < off) s[t] += s[t + off];
        __syncthreads();
    }
    if (t == 0) bsum[blockIdx.x] = s[0];
}

__global__ void k_scan2(int* __restrict__ bsum, int nb, int* __restrict__ ptrN) {
    __shared__ int s[512];
    int t = threadIdx.x;
    int v = (t < nb) ? bsum[t] : 0;
    s[t] = v;
    __syncthreads();
    for (int off = 1; off < 512; off <<= 1) {
        int u = (t >= off) ? s[t - off] : 0;
        __syncthreads();
        s[t] += u;
        __syncthreads();
    }
    if (t < nb) bsum[t] = s[t] - v;          // exclusive block offset
    if (t == nb - 1) *ptrN = s[t];           // total = ptr[N_NODES]
}

__global__ void k_scan3(const int* __restrict__ deg, const int* __restrict__ bsum,
                        int* __restrict__ ptr) {
    __shared__ int s[SCAN_B];
    int t = threadIdx.x;
    int i = blockIdx.x * SCAN_B + t;
    int v = (i < N_NODES) ? deg[i] : 0;
    s[t] = v;
    __syncthreads();
    for (int off = 1; off < SCAN_B; off <<= 1) {
        int u = (t >= off) ? s[t - off] : 0;
        __syncthreads();
        s[t] += u;
        __syncthreads();
    }
    if (i < N_NODES) ptr[i] = bsum[blockIdx.x] + s[t] - v;  // exclusive
}

// ---------------- CSR fill: NO atomics (pos = ptr[d] + rank[i]) ----------------
__global__ void k_fill(const int* __restrict__ src, const int* __restrict__ dst,
                       const int* __restrict__ rank,
                       const int* __restrict__ deg, const int* __restrict__ ptr,
                       int2* __restrict__ edges) {
    int i = blockIdx.x * blockDim.x + threadIdx.x;
    if (i < N_EDGES) {
        int s = src[i], d = dst[i];
        int ds = deg[s], dd = deg[d];
        float ns = (ds > 0) ? rsqrtf((float)ds) : 0.0f;
        float nd = (dd > 0) ? rsqrtf((float)dd) : 0.0f;
        int pos = ptr[d] + rank[i];
        edges[pos] = make_int2(s, __float_as_int(ns * nd));
    }
}

// ---------------- node feature init (fp16 out): x = [emb || relu(sf@pw+pb)] ----------------
__global__ void k_node_init(const float* __restrict__ emb, const float* __restrict__ sfeat,
                            const float* __restrict__ pw, const float* __restrict__ pb,
                            __half* __restrict__ x) {
    int idx = blockIdx.x * blockDim.x + threadIdx.x;
    if (idx >= N_NODES * HIDDEN) return;
    int n = idx >> 7, c = idx & 127;
    float v;
    if (c < EMB_DIM) {
        v = emb[n * EMB_DIM + c];
    } else {
        int j = c - EMB_DIM;
        float a = pb[j];
        #pragma unroll
        for (int k = 0; k < NSTRUCT; ++k) a += sfeat[n * NSTRUCT + k] * pw[k * NSTRUCT + j];
        v = fmaxf(a, 0.0f);
    }
    x[idx] = __float2half(v);
}

// ---------------- W transpose+cvt: Wt[l][n][k] = (half)W[l][k][n] ----------------
__global__ void k_wcvt(const float* __restrict__ W, __half* __restrict__ Wt) {
    int idx = blockIdx.x * blockDim.x + threadIdx.x;       // 3*128*128
    int l = idx >> 14, rem = idx & 16383, n = rem >> 7, k = rem & 127;
    Wt[idx] = __float2half(W[l * 16384 + k * 128 + n]);
}

// ---------------- MFMA GEMM: h = (half)(xh @ W), fp16 in, fp32 accumulate ----------------
// Block 256 thr = 4 waves; block tile 64 rows; wave tile 16 rows x 128 cols.
// A-frag: lane&15 = row m, k = kc*32 + (lane>>4)*8 + i  (direct fp16 16B load)
// B-frag: lane&15 = col n, same k mapping, from Wt[n][k] fp16 (L2-hot)
// C/D: col = lane&15, row = (lane>>4)*4 + reg   [m89-verified mapping]
__global__ __launch_bounds__(256)
void k_gemm(const __half* __restrict__ xh, const __half* __restrict__ Wt,
            __half* __restrict__ h) {
    const int tid  = threadIdx.x;
    const int w    = tid >> 6;
    const int lane = tid & 63;
    const int g    = lane >> 4;
    const int m15  = lane & 15;

    const int rowA = blockIdx.x * 64 + w * 16 + m15;
    const bool rok = (rowA < N_NODES);

    f32x4 acc[8];
    #pragma unroll
    for (int nt = 0; nt < 8; ++nt) acc[nt] = (f32x4){0.f, 0.f, 0.f, 0.f};

    #pragma unroll
    for (int kc = 0; kc < 4; ++kc) {
        const int k0 = kc * 32 + g * 8;
        f16x8 a = rok ? *reinterpret_cast<const f16x8*>(xh + (size_t)rowA * HIDDEN + k0)
                      : (f16x8)(_Float16)0;
        #pragma unroll
        for (int nt = 0; nt < 8; ++nt) {
            const int n = nt * 16 + m15;
            f16x8 b = *reinterpret_cast<const f16x8*>(Wt + (size_t)n * HIDDEN + k0);
            acc[nt] = __builtin_amdgcn_mfma_f32_16x16x32_f16(a, b, acc[nt], 0, 0, 0);
        }
    }

    const int growbase = blockIdx.x * 64 + w * 16 + g * 4;
    #pragma unroll
    for (int nt = 0; nt < 8; ++nt) {
        const int col = nt * 16 + m15;
        #pragma unroll
        for (int r = 0; r < 4; ++r) {
            const int grow = growbase + r;
            if (grow < N_NODES)
                h[(size_t)grow * HIDDEN + col] = __float2half(acc[nt][r]);
        }
    }
}

// ---------------- aggregation + fused bias/BN/ReLU/residual ----------------
// One wave per node, h fp16. Quarter q handles edge jj+q; sl owns 8 cols
// (16B uint4). fma_mix (no explicit cvt), unroll 4 -> 4 gathers in flight.
// Output: fp16 yh (next-layer input) and/or fp32 yf (final). Residual fp16.
__global__ __launch_bounds__(256)
void k_agg(const __half* __restrict__ h, const int* __restrict__ ptr,
           const int2* __restrict__ edges,
           const float* __restrict__ bias, const float* __restrict__ mean,
           const float* __restrict__ var, const float* __restrict__ gamma,
           const float* __restrict__ beta,
           const __half* __restrict__ xprev, int has_resid,
           __half* __restrict__ yh, float* __restrict__ yf) {
    int node = blockIdx.x * 4 + (threadIdx.x >> 6);
    if (node >= N_NODES) return;
    const int lane = threadIdx.x & 63;
    const int q    = lane >> 4;
    const int sl   = lane & 15;
    const int c0   = sl * 8;
    int s = ptr[node], e = ptr[node + 1];

    float acc[8];
    #pragma unroll
    for (int k = 0; k < 8; ++k) acc[k] = 0.0f;

    for (int j0 = s; j0 < e; j0 += 64) {
        int nb  = min(64, e - j0);
        int idx = j0 + lane;
        int2 rec = (idx < e) ? edges[idx] : make_int2(0, 0);
        #pragma unroll 4
        for (int jj = 0; jj < nb; jj += 4) {
            int   sv = __shfl(rec.x, jj + q);
            float nv = __int_as_float(__shfl(rec.y, jj + q));
            uint4 v = *reinterpret_cast<const uint4*>(h + ((size_t)sv << 7) + c0);
            const __half* hv = reinterpret_cast<const __half*>(&v);
            #pragma unroll
            for (int k = 0; k < 8; ++k)
                acc[k] = fmaf(__half2float(hv[k]), nv, acc[k]);   // v_fma_mix
        }
    }

    #pragma unroll
    for (int k = 0; k < 8; ++k) {
        acc[k] += __shfl_xor(acc[k], 16);
        acc[k] += __shfl_xor(acc[k], 32);
    }

    if (q == 0) {
        float4 bi0 = *reinterpret_cast<const float4*>(bias  + c0);
        float4 bi1 = *reinterpret_cast<const float4*>(bias  + c0 + 4);
        float4 mu0 = *reinterpret_cast<const float4*>(mean  + c0);
        float4 mu1 = *reinterpret_cast<const float4*>(mean  + c0 + 4);
        float4 va0 = *reinterpret_cast<const float4*>(var   + c0);
        float4 va1 = *reinterpret_cast<const float4*>(var   + c0 + 4);
        float4 ga0 = *reinterpret_cast<const float4*>(gamma + c0);
        float4 ga1 = *reinterpret_cast<const float4*>(gamma + c0 + 4);
        float4 be0 = *reinterpret_cast<const float4*>(beta  + c0);
        float4 be1 = *reinterpret_cast<const float4*>(beta  + c0 + 4);
        float y[8];
        y[0] = fmaxf((acc[0] + bi0.x - mu0.x) * (ga0.x * rsqrtf(va0.x + BN_EPS)) + be0.x, 0.0f);
        y[1] = fmaxf((acc[1] + bi0.y - mu0.y) * (ga0.y * rsqrtf(va0.y + BN_EPS)) + be0.y, 0.0f);
        y[2] = fmaxf((acc[2] + bi0.z - mu0.z) * (ga0.z * rsqrtf(va0.z + BN_EPS)) + be0.z, 0.0f);
        y[3] = fmaxf((acc[3] + bi0.w - mu0.w) * (ga0.w * rsqrtf(va0.w + BN_EPS)) + be0.w, 0.0f);
        y[4] = fmaxf((acc[4] + bi1.x - mu1.x) * (ga1.x * rsqrtf(va1.x + BN_EPS)) + be1.x, 0.0f);
        y[5] = fmaxf((acc[5] + bi1.y - mu1.y) * (ga1.y * rsqrtf(va1.y + BN_EPS)) + be1.y, 0.0f);
        y[6] = fmaxf((acc[6] + bi1.z - mu1.z) * (ga1.z * rsqrtf(va1.z + BN_EPS)) + be1.z, 0.0f);
        y[7] = fmaxf((acc[7] + bi1.w - mu1.w) * (ga1.w * rsqrtf(va1.w + BN_EPS)) + be1.w, 0.0f);
        size_t o = ((size_t)node << 7) + c0;
        if (has_resid) {
            uint4 xp = *reinterpret_cast<const uint4*>(xprev + o);
            const __half* xh = reinterpret_cast<const __half*>(&xp);
            #pragma unroll
            for (int k = 0; k < 8; ++k)
                y[k] = fmaf(0.5f, __half2float(xh[k]), y[k]);
        }
        if (yh) {
            union { uint4 u; __half2 h2[4]; } p;
            #pragma unroll
            for (int k = 0; k < 4; ++k)
                p.h2[k] = __floats2half2_rn(y[2 * k], y[2 * k + 1]);
            *reinterpret_cast<uint4*>(yh + o) = p.u;
        }
        if (yf) {
            *reinterpret_cast<float4*>(yf + o)     = make_float4(y[0], y[1], y[2], y[3]);
            *reinterpret_cast<float4*>(yf + o + 4) = make_float4(y[4], y[5], y[6], y[7]);
        }
    }
}

// ---------------- launch ----------------
extern "C" void kernel_launch(void* const* d_in, const int* in_sizes, int n_in,
                              void* d_out, int out_size, void* d_ws, size_t ws_size,
                              hipStream_t stream) {
    const int*   ei    = (const int*)d_in[0];
    const int*   src   = ei;
    const int*   dst   = ei + N_EDGES;
    const float* sfeat = (const float*)d_in[1];
    const float* emb   = (const float*)d_in[2];
    const float* pw    = (const float*)d_in[3];
    const float* pb    = (const float*)d_in[4];
    const float* convw = (const float*)d_in[5];
    const float* convb = (const float*)d_in[6];
    const float* gamma = (const float*)d_in[7];
    const float* beta  = (const float*)d_in[8];
    const float* mean  = (const float*)d_in[9];
    const float* var   = (const float*)d_in[10];
    float* out = (float*)d_out;

    char* wsc = (char*)d_ws;
    auto alloc = [&](size_t bytes) -> void* {
        void* p = (void*)wsc;
        wsc += (bytes + 255) & ~(size_t)255;
        return p;
    };
    int*    deg   = (int*)   alloc(N_NODES * sizeof(int));
    int*    rank  = (int*)   alloc((size_t)N_EDGES * sizeof(int));
    int*    ptr   = (int*)   alloc((N_NODES + 1) * sizeof(int));
    int*    bsum  = (int*)   alloc(512 * sizeof(int));
    int2*   edges = (int2*)  alloc((size_t)N_EDGES * sizeof(int2));
    __half* xhA   = (__half*)alloc((size_t)N_NODES * HIDDEN * sizeof(__half));
    __half* xhB   = (__half*)alloc((size_t)N_NODES * HIDDEN * sizeof(__half));
    __half* hbuf  = (__half*)alloc((size_t)N_NODES * HIDDEN * sizeof(__half));
    __half* wt    = (__half*)alloc(3 * HIDDEN * HIDDEN * sizeof(__half));

    const int nb = (N_NODES + SCAN_B - 1) / SCAN_B;   // 391

    hipMemsetAsync(deg, 0, N_NODES * sizeof(int), stream);

    k_count_deg<<<N_EDGES / 256, 256, 0, stream>>>(dst, deg, rank);
    k_wcvt<<<(3 * HIDDEN * HIDDEN) / 256, 256, 0, stream>>>(convw, wt);
    k_scan1<<<nb, SCAN_B, 0, stream>>>(deg, bsum);
    k_scan2<<<1, 512, 0, stream>>>(bsum, nb, &ptr[N_NODES]);
    k_scan3<<<nb, SCAN_B, 0, stream>>>(deg, bsum, ptr);
    k_fill<<<N_EDGES / 256, 256, 0, stream>>>(src, dst, rank, deg, ptr, edges);
    k_node_init<<<(N_NODES * HIDDEN) / 256, 256, 0, stream>>>(emb, sfeat, pw, pb, xhA);

    const int ggrid = (N_NODES + 63) / 64;     // 1563
    const int agrid = (N_NODES + 3) / 4;       // 25000

    // layer 0: x1(xhB) <- agg(gemm(x0=xhA)), no residual
    k_gemm<<<ggrid, 256, 0, stream>>>(xhA, wt + 0 * HIDDEN * HIDDEN, hbuf);
    k_agg<<<agrid, 256, 0, stream>>>(hbuf, ptr, edges,
                                     convb + 0 * HIDDEN, mean + 0 * HIDDEN, var + 0 * HIDDEN,
                                     gamma + 0 * HIDDEN, beta + 0 * HIDDEN,
                                     nullptr, 0, xhB, nullptr);
    // layer 1: x2(xhA) <- agg(gemm(x1=xhB)) + 0.5*x1
    k_gemm<<<ggrid, 256, 0, stream>>>(xhB, wt + 1 * HIDDEN * HIDDEN, hbuf);
    k_agg<<<agrid, 256, 0, stream>>>(hbuf, ptr, edges,
                                     convb + 1 * HIDDEN, mean + 1 * HIDDEN, var + 1 * HIDDEN,
                                     gamma + 1 * HIDDEN, beta + 1 * HIDDEN,
                                     xhB, 1, xhA, nullptr);
    // layer 2: out(fp32) <- agg(gemm(x2=xhA)) + 0.5*x2
    k_gemm<<<ggrid, 256, 0, stream>>>(xhA, wt + 2 * HIDDEN * HIDDEN, hbuf);
    k_agg<<<agrid, 256, 0, stream>>>(hbuf, ptr, edges,
                                     convb + 2 * HIDDEN, mean + 2 * HIDDEN, var + 2 * HIDDEN,
                                     gamma + 2 * HIDDEN, beta + 2 * HIDDEN,
                                     xhA, 1, nullptr, out);
    (void)in_sizes; (void)n_in; (void)out_size; (void)ws_size;
}